// Round 4
// baseline (332.312 us; speedup 1.0000x reference)
//
#include <hip/hip_runtime.h>

#define S_   2048
#define D_   1024
#define H_   16
#define HD_  64
#define NTOK 8192   // B*S
#define QKS  2048   // row stride of fused QK output
#define QSCALE 0.18033688f  // 0.125 * log2(e) — folded into Q at projection time

typedef __attribute__((ext_vector_type(8))) __bf16 bf16x8;
typedef __attribute__((ext_vector_type(4))) float  f32x4;

#define GPTR(p) ((__attribute__((address_space(1))) void*)(unsigned long long)(p))
#define LPTR(p) ((__attribute__((address_space(3))) void*)(p))

// ---------------- fused prep: cast x -> bf16, transpose 4 weights ----------------
__global__ __launch_bounds__(256) void k_prep(const float* __restrict__ x,
                                              __bf16* __restrict__ xb,
                                              const float* __restrict__ Wq,
                                              const float* __restrict__ Wk,
                                              const float* __restrict__ Wv,
                                              const float* __restrict__ Wo,
                                              __bf16* __restrict__ wqkt,
                                              __bf16* __restrict__ wvt,
                                              __bf16* __restrict__ wot) {
    const int bx = blockIdx.x;
    if (bx < 4096) {
        int i = bx * 2048 + threadIdx.x * 8;
        f32x4 a = *(const f32x4*)(x + i);
        f32x4 b = *(const f32x4*)(x + i + 4);
        bf16x8 o;
#pragma unroll
        for (int j = 0; j < 4; j++) { o[j] = (__bf16)a[j]; o[4 + j] = (__bf16)b[j]; }
        *(bf16x8*)(xb + i) = o;
        return;
    }
    __shared__ float t[32][33];
    const int tt = bx - 4096;
    const int widx = tt >> 10, r = tt & 1023;
    const float* W;
    __bf16* Wt;
    switch (widx) {
        case 0: W = Wq; Wt = wqkt; break;
        case 1: W = Wk; Wt = wqkt + (size_t)D_ * D_; break;
        case 2: W = Wv; Wt = wvt; break;
        default: W = Wo; Wt = wot; break;
    }
    const int i0 = (r & 31) * 32, j0 = (r >> 5) * 32;
    const int tx = threadIdx.x & 31, ty = threadIdx.x >> 5;
#pragma unroll
    for (int rr = 0; rr < 32; rr += 8)
        t[ty + rr][tx] = W[(size_t)(i0 + ty + rr) * D_ + j0 + tx];
    __syncthreads();
#pragma unroll
    for (int rr = 0; rr < 32; rr += 8)
        Wt[(size_t)(j0 + ty + rr) * D_ + i0 + tx] = (__bf16)t[tx][ty + rr];
}

// ---------------- shared GEMM body (bf16 out, optional scale) ----------------
__device__ __forceinline__ void gemm_body_bf16(const __bf16* __restrict__ A,
                                               const __bf16* __restrict__ Bt,
                                               __bf16* __restrict__ C,
                                               int N, int K, int tm, int tn,
                                               float scale,
                                               __bf16* As, __bf16* Bs) {
    const int tid  = threadIdx.x;
    const int wave = tid >> 6, lane = tid & 63;
    const int quad = lane >> 4, l16 = lane & 15;
    const int wm = (wave & 1) * 64, wn = (wave >> 1) * 64;
    f32x4 acc[4][4] = {};

    for (int k0 = 0; k0 < K; k0 += 32) {
        __syncthreads();
#pragma unroll
        for (int s = 0; s < 2; s++) {
            const int cb = s * 256 + wave * 64;
            const int c  = cb + lane;
            const int row = c >> 2, kc = (c & 3) * 8;
            __builtin_amdgcn_global_load_lds(GPTR(A + (size_t)(tm + row) * K + k0 + kc),
                                             LPTR(As + cb * 8), 16, 0, 0);
            __builtin_amdgcn_global_load_lds(GPTR(Bt + (size_t)(tn + row) * K + k0 + kc),
                                             LPTR(Bs + cb * 8), 16, 0, 0);
        }
        __syncthreads();

        bf16x8 af[4], bf[4];
#pragma unroll
        for (int mi = 0; mi < 4; mi++)
            af[mi] = *(const bf16x8*)&As[(wm + mi * 16 + l16) * 32 + quad * 8];
#pragma unroll
        for (int ni = 0; ni < 4; ni++)
            bf[ni] = *(const bf16x8*)&Bs[(wn + ni * 16 + l16) * 32 + quad * 8];
#pragma unroll
        for (int mi = 0; mi < 4; mi++)
#pragma unroll
            for (int ni = 0; ni < 4; ni++)
                acc[mi][ni] = __builtin_amdgcn_mfma_f32_16x16x32_bf16(
                    af[mi], bf[ni], acc[mi][ni], 0, 0, 0);
    }

#pragma unroll
    for (int mi = 0; mi < 4; mi++)
#pragma unroll
        for (int ni = 0; ni < 4; ni++)
#pragma unroll
            for (int r = 0; r < 4; r++) {
                const int row = tm + wm + mi * 16 + quad * 4 + r;
                const int col = tn + wn + ni * 16 + l16;
                C[(size_t)row * N + col] = (__bf16)(acc[mi][ni][r] * scale);
            }
}

// ---------------- fused QKV projection ----------------
__global__ __launch_bounds__(256) void k_gemm_qkv(const __bf16* __restrict__ xb,
                                                  const __bf16* __restrict__ wqkt,
                                                  const __bf16* __restrict__ wvt,
                                                  __bf16* __restrict__ qk,
                                                  __bf16* __restrict__ VT) {
    __shared__ __bf16 As[128 * 32];
    __shared__ __bf16 Bs[128 * 32];
    const int bx = blockIdx.x;
    if (bx < 1024) {
        const int tm = (bx & 63) * 128, tn = (bx >> 6) * 128;
        const float scale = (tn < D_) ? QSCALE : 1.0f;
        gemm_body_bf16(xb, wqkt, qk, QKS, D_, tm, tn, scale, As, Bs);
    } else {
        const int b2 = bx - 1024;
        const int tm = (b2 & 7) * 128, tn = (b2 >> 3) * 128;
        gemm_body_bf16(wvt, xb, VT, NTOK, D_, tm, tn, 1.0f, As, Bs);
    }
}

// ---------------- output GEMM: out = ctx Wo + bo (fp32 epilogue) ----------------
__global__ __launch_bounds__(256) void k_gemm_o(const __bf16* __restrict__ A,
                                                const __bf16* __restrict__ Bt,
                                                float* __restrict__ C,
                                                const float* __restrict__ bias) {
    __shared__ __bf16 As[128 * 32];
    __shared__ __bf16 Bs[128 * 32];
    const int tid  = threadIdx.x;
    const int wave = tid >> 6, lane = tid & 63;
    const int quad = lane >> 4, l16 = lane & 15;
    const int tm = blockIdx.x * 128, tn = blockIdx.y * 128;
    const int wm = (wave & 1) * 64, wn = (wave >> 1) * 64;
    const int N = D_, K = D_;
    f32x4 acc[4][4] = {};

    for (int k0 = 0; k0 < K; k0 += 32) {
        __syncthreads();
#pragma unroll
        for (int s = 0; s < 2; s++) {
            const int cb = s * 256 + wave * 64;
            const int c  = cb + lane;
            const int row = c >> 2, kc = (c & 3) * 8;
            __builtin_amdgcn_global_load_lds(GPTR(A + (size_t)(tm + row) * K + k0 + kc),
                                             LPTR(As + cb * 8), 16, 0, 0);
            __builtin_amdgcn_global_load_lds(GPTR(Bt + (size_t)(tn + row) * K + k0 + kc),
                                             LPTR(Bs + cb * 8), 16, 0, 0);
        }
        __syncthreads();

        bf16x8 af[4], bf[4];
#pragma unroll
        for (int mi = 0; mi < 4; mi++)
            af[mi] = *(const bf16x8*)&As[(wm + mi * 16 + l16) * 32 + quad * 8];
#pragma unroll
        for (int ni = 0; ni < 4; ni++)
            bf[ni] = *(const bf16x8*)&Bs[(wn + ni * 16 + l16) * 32 + quad * 8];
#pragma unroll
        for (int mi = 0; mi < 4; mi++)
#pragma unroll
            for (int ni = 0; ni < 4; ni++)
                acc[mi][ni] = __builtin_amdgcn_mfma_f32_16x16x32_bf16(
                    af[mi], bf[ni], acc[mi][ni], 0, 0, 0);
    }

#pragma unroll
    for (int mi = 0; mi < 4; mi++)
#pragma unroll
        for (int ni = 0; ni < 4; ni++)
#pragma unroll
            for (int r = 0; r < 4; r++) {
                const int row = tm + wm + mi * 16 + quad * 4 + r;
                const int col = tn + wn + ni * 16 + l16;
                C[(size_t)row * N + col] = acc[mi][ni][r] + bias[col];
            }
}

// ---------------- causal flash attention, R4 ----------------
// grid (16, H, B), 128 threads (2 waves). qt = 15-bx (LPT: big blocks first).
// Each wave owns 64 q-rows. KV LDS double-buffered + XOR-swizzled; P per-wave.
// 1024 blocks, LDS 50 KB -> 3 blocks/CU.
__global__ __launch_bounds__(128, 2) void k_attn(const __bf16* __restrict__ Qb,
                                                 const __bf16* __restrict__ Kb,
                                                 const __bf16* __restrict__ VT,
                                                 __bf16* __restrict__ ctx) {
    __shared__ __bf16 Ks[2][64 * 64];   // 16 KB
    __shared__ __bf16 Vs[2][64 * 64];   // 16 KB
    __shared__ __bf16 P[2][64 * 72];    // 18 KB, per-wave private (stride 144B)

    const int tid = threadIdx.x;
    const int wave = tid >> 6, lane = tid & 63;
    const int quad = lane >> 4, l16 = lane & 15;
    const int h = blockIdx.y, b = blockIdx.z;
    const size_t tok0 = (size_t)b * S_;
    const size_t hoff = (size_t)h * HD_;

    const int qt = 15 - blockIdx.x;     // LPT dispatch order
    const int qb = qt * 128;
    const int q0 = qb + wave * 64;

    bf16x8 onesv;
#pragma unroll
    for (int j = 0; j < 8; j++) onesv[j] = (__bf16)1.0f;

    auto stage = [&](int kv, int buf) {
#pragma unroll
        for (int s = 0; s < 4; s++) {
            const int cb = s * 128 + wave * 64;   // wave-uniform chunk base
            const int c  = cb + lane;
            const int row = c >> 3;
            const int gc  = (c & 7) ^ (row & 7);  // XOR swizzle
            __builtin_amdgcn_global_load_lds(
                GPTR(Kb + (size_t)(tok0 + kv + row) * QKS + hoff + gc * 8),
                LPTR(&Ks[buf][cb * 8]), 16, 0, 0);
            __builtin_amdgcn_global_load_lds(
                GPTR(VT + (hoff + row) * (size_t)NTOK + tok0 + kv + gc * 8),
                LPTR(&Vs[buf][cb * 8]), 16, 0, 0);
        }
    };

    // Q fragments: A[m = qi*16 + l16][k = quad*8+j] (Q pre-scaled by 0.125*log2e)
    bf16x8 qf[4][2];
#pragma unroll
    for (int qi = 0; qi < 4; qi++)
#pragma unroll
        for (int ks = 0; ks < 2; ks++)
            qf[qi][ks] = *(const bf16x8*)&Qb[(tok0 + q0 + qi * 16 + l16) * QKS +
                                             hoff + ks * 32 + quad * 8];

    f32x4 oacc[4][4] = {};
    f32x4 lacc[4] = {};
    const int ktb = 2 * qt + 1;

    stage(0, 0);
    __syncthreads();

    for (int kt = 0; kt <= ktb; kt++) {
        const int cur = kt & 1;
        const int kv0 = kt * 64;
        if (kt < ktb) stage(kv0 + 64, 1 - cur);   // prefetch overlaps compute

        if (kv0 <= q0) {                          // wave participates (causal)
            const bool diag = (kv0 == q0);
            // QK^T, ksub-outer (sacc transient = 16 VGPRs)
#pragma unroll
            for (int ksub = 0; ksub < 4; ksub++) {
                const int krow = ksub * 16 + l16;
                bf16x8 kf0 = *(const bf16x8*)
                    &Ks[cur][(krow * 8 + ((quad) ^ (krow & 7))) * 8];
                bf16x8 kf1 = *(const bf16x8*)
                    &Ks[cur][(krow * 8 + ((4 + quad) ^ (krow & 7))) * 8];
                f32x4 s[4];
#pragma unroll
                for (int qi = 0; qi < 4; qi++) {
                    s[qi] = __builtin_amdgcn_mfma_f32_16x16x32_bf16(
                        qf[qi][0], kf0, (f32x4){0.f, 0.f, 0.f, 0.f}, 0, 0, 0);
                    s[qi] = __builtin_amdgcn_mfma_f32_16x16x32_bf16(
                        qf[qi][1], kf1, s[qi], 0, 0, 0);
                }
                if (diag) {
#pragma unroll
                    for (int qi = 0; qi < 4; qi++)
#pragma unroll
                        for (int r = 0; r < 4; r++) {
                            const int kg = kv0 + krow;
                            const int qg = q0 + qi * 16 + quad * 4 + r;
                            if (kg > qg) s[qi][r] = -1e30f;
                        }
                }
                // p = exp2(s); C-layout -> per-wave LDS for A-layout re-read
#pragma unroll
                for (int qi = 0; qi < 4; qi++)
#pragma unroll
                    for (int r = 0; r < 4; r++)
                        P[wave][(qi * 16 + quad * 4 + r) * 72 + krow] =
                            (__bf16)__builtin_amdgcn_exp2f(s[qi][r]);
            }
            asm volatile("s_waitcnt lgkmcnt(0)" ::: "memory");  // wave-private P
            // O += P V ; l += P * ones
#pragma unroll
            for (int ks2 = 0; ks2 < 2; ks2++) {
                bf16x8 af[4];
#pragma unroll
                for (int qi = 0; qi < 4; qi++)
                    af[qi] = *(const bf16x8*)&P[wave][(qi * 16 + l16) * 72 +
                                                      ks2 * 32 + quad * 8];
#pragma unroll
                for (int qi = 0; qi < 4; qi++)
                    lacc[qi] = __builtin_amdgcn_mfma_f32_16x16x32_bf16(
                        af[qi], onesv, lacc[qi], 0, 0, 0);
#pragma unroll
                for (int hs = 0; hs < 4; hs++) {
                    const int row = hs * 16 + l16;
                    bf16x8 vf = *(const bf16x8*)
                        &Vs[cur][(row * 8 + (((ks2 * 4 + quad) ^ (row & 7)))) * 8];
#pragma unroll
                    for (int qi = 0; qi < 4; qi++)
                        oacc[qi][hs] = __builtin_amdgcn_mfma_f32_16x16x32_bf16(
                            af[qi], vf, oacc[qi][hs], 0, 0, 0);
                }
            }
        }
        __syncthreads();   // buf[cur] readers done; prefetch drained
    }

    // epilogue: ctx = O / l
#pragma unroll
    for (int qi = 0; qi < 4; qi++) {
        f32x4 rl;
#pragma unroll
        for (int r = 0; r < 4; r++) rl[r] = 1.0f / lacc[qi][r];
#pragma unroll
        for (int hs = 0; hs < 4; hs++)
#pragma unroll
            for (int r = 0; r < 4; r++) {
                const int qg = q0 + qi * 16 + quad * 4 + r;
                ctx[(tok0 + qg) * D_ + hoff + hs * 16 + l16] =
                    (__bf16)(oacc[qi][hs][r] * rl[r]);
            }
    }
}

// ---------------- launch ----------------
extern "C" void kernel_launch(void* const* d_in, const int* in_sizes, int n_in,
                              void* d_out, int out_size, void* d_ws, size_t ws_size,
                              hipStream_t stream) {
    const float* x  = (const float*)d_in[0];
    const float* Wq = (const float*)d_in[1];
    const float* Wk = (const float*)d_in[2];
    const float* Wv = (const float*)d_in[3];
    const float* Wo = (const float*)d_in[4];
    const float* bo = (const float*)d_in[5];
    float* out = (float*)d_out;

    char* p = (char*)d_ws;
    __bf16* xb   = (__bf16*)p; p += (size_t)NTOK * D_ * 2;   // 16 MB
    __bf16* wqkt = (__bf16*)p; p += (size_t)2 * D_ * D_ * 2; // 4 MB
    __bf16* wvt  = (__bf16*)p; p += (size_t)D_ * D_ * 2;     // 2 MB
    __bf16* wot  = (__bf16*)p; p += (size_t)D_ * D_ * 2;     // 2 MB
    __bf16* qk   = (__bf16*)p; p += (size_t)NTOK * QKS * 2;  // 32 MB [tok][Q|K]
    __bf16* VT   = (__bf16*)p; p += (size_t)NTOK * D_ * 2;   // 16 MB [d][tok]
    __bf16* ctx  = (__bf16*)p; p += (size_t)NTOK * D_ * 2;   // 16 MB

    k_prep<<<dim3(4096 + 4 * 1024), 256, 0, stream>>>(x, xb, Wq, Wk, Wv, Wo,
                                                      wqkt, wvt, wot);
    k_gemm_qkv<<<dim3(1024 + 512), 256, 0, stream>>>(xb, wqkt, wvt, qk, VT);
    k_attn<<<dim3(16, H_, 4), 128, 0, stream>>>(qk, qk + D_, VT, ctx);
    k_gemm_o<<<dim3(64, 8), 256, 0, stream>>>(ctx, wot, out, bo);
}

// Round 5
// 266.027 us; speedup vs baseline: 1.2492x; 1.2492x over previous
//
#include <hip/hip_runtime.h>

#define S_   2048
#define D_   1024
#define H_   16
#define HD_  64
#define NTOK 8192   // B*S
#define QKS  2048   // row stride of fused QK output
#define QSCALE 0.18033688f  // 0.125 * log2(e) — folded into Q at projection time

typedef __attribute__((ext_vector_type(8))) __bf16 bf16x8;
typedef __attribute__((ext_vector_type(4))) float  f32x4;

#define GPTR(p) ((__attribute__((address_space(1))) void*)(unsigned long long)(p))
#define LPTR(p) ((__attribute__((address_space(3))) void*)(p))

// ---------------- fused prep: cast x -> bf16, transpose 4 weights ----------------
__global__ __launch_bounds__(256) void k_prep(const float* __restrict__ x,
                                              __bf16* __restrict__ xb,
                                              const float* __restrict__ Wq,
                                              const float* __restrict__ Wk,
                                              const float* __restrict__ Wv,
                                              const float* __restrict__ Wo,
                                              __bf16* __restrict__ wqkt,
                                              __bf16* __restrict__ wvt,
                                              __bf16* __restrict__ wot) {
    const int bx = blockIdx.x;
    if (bx < 4096) {
        int i = bx * 2048 + threadIdx.x * 8;
        f32x4 a = *(const f32x4*)(x + i);
        f32x4 b = *(const f32x4*)(x + i + 4);
        bf16x8 o;
#pragma unroll
        for (int j = 0; j < 4; j++) { o[j] = (__bf16)a[j]; o[4 + j] = (__bf16)b[j]; }
        *(bf16x8*)(xb + i) = o;
        return;
    }
    __shared__ float t[32][33];
    const int tt = bx - 4096;
    const int widx = tt >> 10, r = tt & 1023;
    const float* W;
    __bf16* Wt;
    switch (widx) {
        case 0: W = Wq; Wt = wqkt; break;
        case 1: W = Wk; Wt = wqkt + (size_t)D_ * D_; break;
        case 2: W = Wv; Wt = wvt; break;
        default: W = Wo; Wt = wot; break;
    }
    const int i0 = (r & 31) * 32, j0 = (r >> 5) * 32;
    const int tx = threadIdx.x & 31, ty = threadIdx.x >> 5;
#pragma unroll
    for (int rr = 0; rr < 32; rr += 8)
        t[ty + rr][tx] = W[(size_t)(i0 + ty + rr) * D_ + j0 + tx];
    __syncthreads();
#pragma unroll
    for (int rr = 0; rr < 32; rr += 8)
        Wt[(size_t)(j0 + ty + rr) * D_ + i0 + tx] = (__bf16)t[tx][ty + rr];
}

// ---------------- shared GEMM body (bf16 out, optional scale) ----------------
__device__ __forceinline__ void gemm_body_bf16(const __bf16* __restrict__ A,
                                               const __bf16* __restrict__ Bt,
                                               __bf16* __restrict__ C,
                                               int N, int K, int tm, int tn,
                                               float scale,
                                               __bf16* As, __bf16* Bs) {
    const int tid  = threadIdx.x;
    const int wave = tid >> 6, lane = tid & 63;
    const int quad = lane >> 4, l16 = lane & 15;
    const int wm = (wave & 1) * 64, wn = (wave >> 1) * 64;
    f32x4 acc[4][4] = {};

    for (int k0 = 0; k0 < K; k0 += 32) {
        __syncthreads();
#pragma unroll
        for (int s = 0; s < 2; s++) {
            const int cb = s * 256 + wave * 64;
            const int c  = cb + lane;
            const int row = c >> 2, kc = (c & 3) * 8;
            __builtin_amdgcn_global_load_lds(GPTR(A + (size_t)(tm + row) * K + k0 + kc),
                                             LPTR(As + cb * 8), 16, 0, 0);
            __builtin_amdgcn_global_load_lds(GPTR(Bt + (size_t)(tn + row) * K + k0 + kc),
                                             LPTR(Bs + cb * 8), 16, 0, 0);
        }
        __syncthreads();

        bf16x8 af[4], bf[4];
#pragma unroll
        for (int mi = 0; mi < 4; mi++)
            af[mi] = *(const bf16x8*)&As[(wm + mi * 16 + l16) * 32 + quad * 8];
#pragma unroll
        for (int ni = 0; ni < 4; ni++)
            bf[ni] = *(const bf16x8*)&Bs[(wn + ni * 16 + l16) * 32 + quad * 8];
#pragma unroll
        for (int mi = 0; mi < 4; mi++)
#pragma unroll
            for (int ni = 0; ni < 4; ni++)
                acc[mi][ni] = __builtin_amdgcn_mfma_f32_16x16x32_bf16(
                    af[mi], bf[ni], acc[mi][ni], 0, 0, 0);
    }

#pragma unroll
    for (int mi = 0; mi < 4; mi++)
#pragma unroll
        for (int ni = 0; ni < 4; ni++)
#pragma unroll
            for (int r = 0; r < 4; r++) {
                const int row = tm + wm + mi * 16 + quad * 4 + r;
                const int col = tn + wn + ni * 16 + l16;
                C[(size_t)row * N + col] = (__bf16)(acc[mi][ni][r] * scale);
            }
}

// ---------------- fused QKV projection ----------------
__global__ __launch_bounds__(256) void k_gemm_qkv(const __bf16* __restrict__ xb,
                                                  const __bf16* __restrict__ wqkt,
                                                  const __bf16* __restrict__ wvt,
                                                  __bf16* __restrict__ qk,
                                                  __bf16* __restrict__ VT) {
    __shared__ __bf16 As[128 * 32];
    __shared__ __bf16 Bs[128 * 32];
    const int bx = blockIdx.x;
    if (bx < 1024) {
        const int tm = (bx & 63) * 128, tn = (bx >> 6) * 128;
        const float scale = (tn < D_) ? QSCALE : 1.0f;
        gemm_body_bf16(xb, wqkt, qk, QKS, D_, tm, tn, scale, As, Bs);
    } else {
        const int b2 = bx - 1024;
        const int tm = (b2 & 7) * 128, tn = (b2 >> 3) * 128;
        gemm_body_bf16(wvt, xb, VT, NTOK, D_, tm, tn, 1.0f, As, Bs);
    }
}

// ---------------- output GEMM: out = ctx Wo + bo (fp32 epilogue) ----------------
__global__ __launch_bounds__(256) void k_gemm_o(const __bf16* __restrict__ A,
                                                const __bf16* __restrict__ Bt,
                                                float* __restrict__ C,
                                                const float* __restrict__ bias) {
    __shared__ __bf16 As[128 * 32];
    __shared__ __bf16 Bs[128 * 32];
    const int tid  = threadIdx.x;
    const int wave = tid >> 6, lane = tid & 63;
    const int quad = lane >> 4, l16 = lane & 15;
    const int tm = blockIdx.x * 128, tn = blockIdx.y * 128;
    const int wm = (wave & 1) * 64, wn = (wave >> 1) * 64;
    const int N = D_, K = D_;
    f32x4 acc[4][4] = {};

    for (int k0 = 0; k0 < K; k0 += 32) {
        __syncthreads();
#pragma unroll
        for (int s = 0; s < 2; s++) {
            const int cb = s * 256 + wave * 64;
            const int c  = cb + lane;
            const int row = c >> 2, kc = (c & 3) * 8;
            __builtin_amdgcn_global_load_lds(GPTR(A + (size_t)(tm + row) * K + k0 + kc),
                                             LPTR(As + cb * 8), 16, 0, 0);
            __builtin_amdgcn_global_load_lds(GPTR(Bt + (size_t)(tn + row) * K + k0 + kc),
                                             LPTR(Bs + cb * 8), 16, 0, 0);
        }
        __syncthreads();

        bf16x8 af[4], bf[4];
#pragma unroll
        for (int mi = 0; mi < 4; mi++)
            af[mi] = *(const bf16x8*)&As[(wm + mi * 16 + l16) * 32 + quad * 8];
#pragma unroll
        for (int ni = 0; ni < 4; ni++)
            bf[ni] = *(const bf16x8*)&Bs[(wn + ni * 16 + l16) * 32 + quad * 8];
#pragma unroll
        for (int mi = 0; mi < 4; mi++)
#pragma unroll
            for (int ni = 0; ni < 4; ni++)
                acc[mi][ni] = __builtin_amdgcn_mfma_f32_16x16x32_bf16(
                    af[mi], bf[ni], acc[mi][ni], 0, 0, 0);
    }

#pragma unroll
    for (int mi = 0; mi < 4; mi++)
#pragma unroll
        for (int ni = 0; ni < 4; ni++)
#pragma unroll
            for (int r = 0; r < 4; r++) {
                const int row = tm + wm + mi * 16 + quad * 4 + r;
                const int col = tn + wn + ni * 16 + l16;
                C[(size_t)row * N + col] = acc[mi][ni][r] + bias[col];
            }
}

// ---------------- causal flash attention, R5 ----------------
// R3 structure (grid (8,H,B), 256 threads, paired qt {bx,15-bx} -> uniform 36
// iterations/block) with V fragments register-prefetched from global (VT is
// L2-resident) instead of LDS-staged. LDS: Ks dbuf 16K + P 18K = 34 KB.
__global__ __launch_bounds__(256, 2) void k_attn(const __bf16* __restrict__ Qb,
                                                 const __bf16* __restrict__ Kb,
                                                 const __bf16* __restrict__ VT,
                                                 __bf16* __restrict__ ctx) {
    __shared__ __bf16 Ks[2][64 * 64];   // 16 KB, XOR-swizzled 16B chunks
    __shared__ __bf16 P[4][32 * 72];    // 18 KB, per-wave private (stride 144B)

    const int tid = threadIdx.x;
    const int wave = tid >> 6, lane = tid & 63;
    const int quad = lane >> 4, l16 = lane & 15;
    const int h = blockIdx.y, b = blockIdx.z;
    const size_t tok0 = (size_t)b * S_;
    const size_t hoff = (size_t)h * HD_;

    bf16x8 onesv;
#pragma unroll
    for (int j = 0; j < 8; j++) onesv[j] = (__bf16)1.0f;

    auto stage = [&](int kv, int buf) {   // K tile only: 512 x 16B chunks
#pragma unroll
        for (int s = 0; s < 2; s++) {
            const int cb = s * 256 + wave * 64;
            const int c  = cb + lane;
            const int row = c >> 3;
            const int gc  = (c & 7) ^ (row & 7);
            __builtin_amdgcn_global_load_lds(
                GPTR(Kb + (size_t)(tok0 + kv + row) * QKS + hoff + gc * 8),
                LPTR(&Ks[buf][cb * 8]), 16, 0, 0);
        }
    };

#pragma unroll 1
    for (int sidx = 0; sidx < 2; sidx++) {
        const int qt = sidx == 0 ? blockIdx.x : 15 - blockIdx.x;
        const int qb = qt * 128;
        const int q0 = qb + wave * 32;

        bf16x8 qf[2][2];
#pragma unroll
        for (int qi = 0; qi < 2; qi++)
#pragma unroll
            for (int ks = 0; ks < 2; ks++)
                qf[qi][ks] = *(const bf16x8*)&Qb[(tok0 + q0 + qi * 16 + l16) * QKS +
                                                 hoff + ks * 32 + quad * 8];

        f32x4 oacc[2][4] = {};
        f32x4 lacc[2] = {};
        const int ktb = (qb + 127) >> 6;

        stage(0, 0);
        __syncthreads();

        for (int kt = 0; kt <= ktb; kt++) {
            const int cur = kt & 1;
            const int kv0 = kt * 64;
            if (kt < ktb) stage(kv0 + 64, 1 - cur);   // K prefetch overlaps compute

            if (kv0 <= q0 + 31) {
                // V fragments for THIS tile: issue early, consume after QK+softmax.
                // B-frag: lane holds V[kv=quad*8+j][hd = hs*16+l16] -> 16B contiguous.
                bf16x8 vreg[2][4];
#pragma unroll
                for (int ks2 = 0; ks2 < 2; ks2++)
#pragma unroll
                    for (int hs = 0; hs < 4; hs++)
                        vreg[ks2][hs] = *(const bf16x8*)
                            &VT[(hoff + hs * 16 + l16) * (size_t)NTOK + tok0 + kv0 +
                                ks2 * 32 + quad * 8];

                f32x4 sacc[2][4] = {};
#pragma unroll
                for (int ks = 0; ks < 2; ks++)
#pragma unroll
                    for (int ksub = 0; ksub < 4; ksub++) {
                        const int r = ksub * 16 + l16;
                        bf16x8 kf = *(const bf16x8*)
                            &Ks[cur][(r * 8 + (((ks * 4 + quad) ^ (r & 7)))) * 8];
#pragma unroll
                        for (int qi = 0; qi < 2; qi++)
                            sacc[qi][ksub] = __builtin_amdgcn_mfma_f32_16x16x32_bf16(
                                qf[qi][ks], kf, sacc[qi][ksub], 0, 0, 0);
                    }
                if (kv0 + 63 > q0) {
#pragma unroll
                    for (int qi = 0; qi < 2; qi++)
#pragma unroll
                        for (int ksub = 0; ksub < 4; ksub++)
#pragma unroll
                            for (int r = 0; r < 4; r++) {
                                const int kg = kv0 + ksub * 16 + l16;
                                const int qg = q0 + qi * 16 + quad * 4 + r;
                                if (kg > qg) sacc[qi][ksub][r] = -1e30f;
                            }
                }
                // p = exp2(s)  (Q pre-scaled); C-layout -> LDS for A-layout re-read
#pragma unroll
                for (int qi = 0; qi < 2; qi++)
#pragma unroll
                    for (int ksub = 0; ksub < 4; ksub++)
#pragma unroll
                        for (int r = 0; r < 4; r++)
                            P[wave][(qi * 16 + quad * 4 + r) * 72 + ksub * 16 + l16] =
                                (__bf16)__builtin_amdgcn_exp2f(sacc[qi][ksub][r]);
                asm volatile("s_waitcnt lgkmcnt(0)" ::: "memory");  // wave-private P
#pragma unroll
                for (int ks2 = 0; ks2 < 2; ks2++) {
                    bf16x8 af[2];
#pragma unroll
                    for (int qi = 0; qi < 2; qi++)
                        af[qi] = *(const bf16x8*)&P[wave][(qi * 16 + l16) * 72 +
                                                          ks2 * 32 + quad * 8];
#pragma unroll
                    for (int qi = 0; qi < 2; qi++)
                        lacc[qi] = __builtin_amdgcn_mfma_f32_16x16x32_bf16(
                            af[qi], onesv, lacc[qi], 0, 0, 0);
#pragma unroll
                    for (int hs = 0; hs < 4; hs++)
#pragma unroll
                        for (int qi = 0; qi < 2; qi++)
                            oacc[qi][hs] = __builtin_amdgcn_mfma_f32_16x16x32_bf16(
                                af[qi], vreg[ks2][hs], oacc[qi][hs], 0, 0, 0);
                }
            }
            __syncthreads();   // Ks[cur] readers done; prefetch drained
        }

#pragma unroll
        for (int qi = 0; qi < 2; qi++) {
            f32x4 rl;
#pragma unroll
            for (int r = 0; r < 4; r++) rl[r] = 1.0f / lacc[qi][r];
#pragma unroll
            for (int hs = 0; hs < 4; hs++)
#pragma unroll
                for (int r = 0; r < 4; r++) {
                    const int qg = q0 + qi * 16 + quad * 4 + r;
                    ctx[(tok0 + qg) * D_ + hoff + hs * 16 + l16] =
                        (__bf16)(oacc[qi][hs][r] * rl[r]);
                }
        }
    }
}

// ---------------- launch ----------------
extern "C" void kernel_launch(void* const* d_in, const int* in_sizes, int n_in,
                              void* d_out, int out_size, void* d_ws, size_t ws_size,
                              hipStream_t stream) {
    const float* x  = (const float*)d_in[0];
    const float* Wq = (const float*)d_in[1];
    const float* Wk = (const float*)d_in[2];
    const float* Wv = (const float*)d_in[3];
    const float* Wo = (const float*)d_in[4];
    const float* bo = (const float*)d_in[5];
    float* out = (float*)d_out;

    char* p = (char*)d_ws;
    __bf16* xb   = (__bf16*)p; p += (size_t)NTOK * D_ * 2;   // 16 MB
    __bf16* wqkt = (__bf16*)p; p += (size_t)2 * D_ * D_ * 2; // 4 MB
    __bf16* wvt  = (__bf16*)p; p += (size_t)D_ * D_ * 2;     // 2 MB
    __bf16* wot  = (__bf16*)p; p += (size_t)D_ * D_ * 2;     // 2 MB
    __bf16* qk   = (__bf16*)p; p += (size_t)NTOK * QKS * 2;  // 32 MB [tok][Q|K]
    __bf16* VT   = (__bf16*)p; p += (size_t)NTOK * D_ * 2;   // 16 MB [d][tok]
    __bf16* ctx  = (__bf16*)p; p += (size_t)NTOK * D_ * 2;   // 16 MB

    k_prep<<<dim3(4096 + 4 * 1024), 256, 0, stream>>>(x, xb, Wq, Wk, Wv, Wo,
                                                      wqkt, wvt, wot);
    k_gemm_qkv<<<dim3(1024 + 512), 256, 0, stream>>>(xb, wqkt, wvt, qk, VT);
    k_attn<<<dim3(8, H_, 4), 256, 0, stream>>>(qk, qk + D_, VT, ctx);
    k_gemm_o<<<dim3(64, 8), 256, 0, stream>>>(ctx, wot, out, bo);
}

// Round 6
// 250.818 us; speedup vs baseline: 1.3249x; 1.0606x over previous
//
#include <hip/hip_runtime.h>

#define S_   2048
#define D_   1024
#define H_   16
#define HD_  64
#define NTOK 8192   // B*S
#define QKS  2048   // row stride of fused QK output
#define QSCALE 0.18033688f  // 0.125 * log2(e) — folded into Q at projection time

typedef __attribute__((ext_vector_type(8))) __bf16 bf16x8;
typedef __attribute__((ext_vector_type(4))) __bf16 bf16x4;
typedef __attribute__((ext_vector_type(4))) float  f32x4;
typedef __attribute__((ext_vector_type(4))) short  short4v;

#define GPTR(p) ((__attribute__((address_space(1))) void*)(unsigned long long)(p))
#define LPTR(p) ((__attribute__((address_space(3))) void*)(p))

// ---------------- fused prep: cast x -> bf16, transpose 4 weights ----------------
__global__ __launch_bounds__(256) void k_prep(const float* __restrict__ x,
                                              __bf16* __restrict__ xb,
                                              const float* __restrict__ Wq,
                                              const float* __restrict__ Wk,
                                              const float* __restrict__ Wv,
                                              const float* __restrict__ Wo,
                                              __bf16* __restrict__ wqkt,
                                              __bf16* __restrict__ wvt,
                                              __bf16* __restrict__ wot) {
    const int bx = blockIdx.x;
    if (bx < 4096) {
        int i = bx * 2048 + threadIdx.x * 8;
        f32x4 a = *(const f32x4*)(x + i);
        f32x4 b = *(const f32x4*)(x + i + 4);
        bf16x8 o;
#pragma unroll
        for (int j = 0; j < 4; j++) { o[j] = (__bf16)a[j]; o[4 + j] = (__bf16)b[j]; }
        *(bf16x8*)(xb + i) = o;
        return;
    }
    __shared__ float t[32][33];
    const int tt = bx - 4096;
    const int widx = tt >> 10, r = tt & 1023;
    const float* W;
    __bf16* Wt;
    switch (widx) {
        case 0: W = Wq; Wt = wqkt; break;
        case 1: W = Wk; Wt = wqkt + (size_t)D_ * D_; break;
        case 2: W = Wv; Wt = wvt; break;
        default: W = Wo; Wt = wot; break;
    }
    const int i0 = (r & 31) * 32, j0 = (r >> 5) * 32;
    const int tx = threadIdx.x & 31, ty = threadIdx.x >> 5;
#pragma unroll
    for (int rr = 0; rr < 32; rr += 8)
        t[ty + rr][tx] = W[(size_t)(i0 + ty + rr) * D_ + j0 + tx];
    __syncthreads();
#pragma unroll
    for (int rr = 0; rr < 32; rr += 8)
        Wt[(size_t)(j0 + ty + rr) * D_ + i0 + tx] = (__bf16)t[tx][ty + rr];
}

// ---------------- shared GEMM body (bf16 out, optional scale) ----------------
__device__ __forceinline__ void gemm_body_bf16(const __bf16* __restrict__ A,
                                               const __bf16* __restrict__ Bt,
                                               __bf16* __restrict__ C,
                                               int N, int K, int tm, int tn,
                                               float scale,
                                               __bf16* As, __bf16* Bs) {
    const int tid  = threadIdx.x;
    const int wave = tid >> 6, lane = tid & 63;
    const int quad = lane >> 4, l16 = lane & 15;
    const int wm = (wave & 1) * 64, wn = (wave >> 1) * 64;
    f32x4 acc[4][4] = {};

    for (int k0 = 0; k0 < K; k0 += 32) {
        __syncthreads();
#pragma unroll
        for (int s = 0; s < 2; s++) {
            const int cb = s * 256 + wave * 64;
            const int c  = cb + lane;
            const int row = c >> 2, kc = (c & 3) * 8;
            __builtin_amdgcn_global_load_lds(GPTR(A + (size_t)(tm + row) * K + k0 + kc),
                                             LPTR(As + cb * 8), 16, 0, 0);
            __builtin_amdgcn_global_load_lds(GPTR(Bt + (size_t)(tn + row) * K + k0 + kc),
                                             LPTR(Bs + cb * 8), 16, 0, 0);
        }
        __syncthreads();

        bf16x8 af[4], bf[4];
#pragma unroll
        for (int mi = 0; mi < 4; mi++)
            af[mi] = *(const bf16x8*)&As[(wm + mi * 16 + l16) * 32 + quad * 8];
#pragma unroll
        for (int ni = 0; ni < 4; ni++)
            bf[ni] = *(const bf16x8*)&Bs[(wn + ni * 16 + l16) * 32 + quad * 8];
#pragma unroll
        for (int mi = 0; mi < 4; mi++)
#pragma unroll
            for (int ni = 0; ni < 4; ni++)
                acc[mi][ni] = __builtin_amdgcn_mfma_f32_16x16x32_bf16(
                    af[mi], bf[ni], acc[mi][ni], 0, 0, 0);
    }

#pragma unroll
    for (int mi = 0; mi < 4; mi++)
#pragma unroll
        for (int ni = 0; ni < 4; ni++)
#pragma unroll
            for (int r = 0; r < 4; r++) {
                const int row = tm + wm + mi * 16 + quad * 4 + r;
                const int col = tn + wn + ni * 16 + l16;
                C[(size_t)row * N + col] = (__bf16)(acc[mi][ni][r] * scale);
            }
}

// ---------------- fused QKV projection ----------------
__global__ __launch_bounds__(256) void k_gemm_qkv(const __bf16* __restrict__ xb,
                                                  const __bf16* __restrict__ wqkt,
                                                  const __bf16* __restrict__ wvt,
                                                  __bf16* __restrict__ qk,
                                                  __bf16* __restrict__ VT) {
    __shared__ __bf16 As[128 * 32];
    __shared__ __bf16 Bs[128 * 32];
    const int bx = blockIdx.x;
    if (bx < 1024) {
        const int tm = (bx & 63) * 128, tn = (bx >> 6) * 128;
        const float scale = (tn < D_) ? QSCALE : 1.0f;
        gemm_body_bf16(xb, wqkt, qk, QKS, D_, tm, tn, scale, As, Bs);
    } else {
        const int b2 = bx - 1024;
        const int tm = (b2 & 7) * 128, tn = (b2 >> 3) * 128;
        gemm_body_bf16(wvt, xb, VT, NTOK, D_, tm, tn, 1.0f, As, Bs);
    }
}

// ---------------- output GEMM: out = ctx Wo + bo (fp32 epilogue) ----------------
__global__ __launch_bounds__(256) void k_gemm_o(const __bf16* __restrict__ A,
                                                const __bf16* __restrict__ Bt,
                                                float* __restrict__ C,
                                                const float* __restrict__ bias) {
    __shared__ __bf16 As[128 * 32];
    __shared__ __bf16 Bs[128 * 32];
    const int tid  = threadIdx.x;
    const int wave = tid >> 6, lane = tid & 63;
    const int quad = lane >> 4, l16 = lane & 15;
    const int tm = blockIdx.x * 128, tn = blockIdx.y * 128;
    const int wm = (wave & 1) * 64, wn = (wave >> 1) * 64;
    const int N = D_, K = D_;
    f32x4 acc[4][4] = {};

    for (int k0 = 0; k0 < K; k0 += 32) {
        __syncthreads();
#pragma unroll
        for (int s = 0; s < 2; s++) {
            const int cb = s * 256 + wave * 64;
            const int c  = cb + lane;
            const int row = c >> 2, kc = (c & 3) * 8;
            __builtin_amdgcn_global_load_lds(GPTR(A + (size_t)(tm + row) * K + k0 + kc),
                                             LPTR(As + cb * 8), 16, 0, 0);
            __builtin_amdgcn_global_load_lds(GPTR(Bt + (size_t)(tn + row) * K + k0 + kc),
                                             LPTR(Bs + cb * 8), 16, 0, 0);
        }
        __syncthreads();

        bf16x8 af[4], bf[4];
#pragma unroll
        for (int mi = 0; mi < 4; mi++)
            af[mi] = *(const bf16x8*)&As[(wm + mi * 16 + l16) * 32 + quad * 8];
#pragma unroll
        for (int ni = 0; ni < 4; ni++)
            bf[ni] = *(const bf16x8*)&Bs[(wn + ni * 16 + l16) * 32 + quad * 8];
#pragma unroll
        for (int mi = 0; mi < 4; mi++)
#pragma unroll
            for (int ni = 0; ni < 4; ni++)
                acc[mi][ni] = __builtin_amdgcn_mfma_f32_16x16x32_bf16(
                    af[mi], bf[ni], acc[mi][ni], 0, 0, 0);
    }

#pragma unroll
    for (int mi = 0; mi < 4; mi++)
#pragma unroll
        for (int ni = 0; ni < 4; ni++)
#pragma unroll
            for (int r = 0; r < 4; r++) {
                const int row = tm + wm + mi * 16 + quad * 4 + r;
                const int col = tn + wn + ni * 16 + l16;
                C[(size_t)row * N + col] = acc[mi][ni][r] + bias[col];
            }
}

__device__ __forceinline__ short bf16_bits(float f) {
    __bf16 h = (__bf16)f;
    return __builtin_bit_cast(short, h);
}

// ---------------- causal flash attention, R6 ----------------
// R3 skeleton (grid (8,H,B), 256 threads, paired qt {bx,15-bx}); S computed
// TRANSPOSED (S^T = K·Q^T) so P^T stays in registers as the B-operand of
// K=16 MFMAs: O^T = V^T · P^T. No P LDS round-trip, no ones-MFMA; l via
// in-lane adds + shfl_xor. LDS = Ks+Vs dbuf = 32 KB.
__global__ __launch_bounds__(256, 2) void k_attn(const __bf16* __restrict__ Qb,
                                                 const __bf16* __restrict__ Kb,
                                                 const __bf16* __restrict__ VT,
                                                 __bf16* __restrict__ ctx) {
    __shared__ __bf16 Ks[2][64 * 64];   // [kv][hd], 16B-chunk XOR-swizzled
    __shared__ __bf16 Vs[2][64 * 64];   // [hd][kv], 16B-chunk XOR-swizzled

    const int tid = threadIdx.x;
    const int wave = tid >> 6, lane = tid & 63;
    const int quad = lane >> 4, l16 = lane & 15;
    const int h = blockIdx.y, b = blockIdx.z;
    const size_t tok0 = (size_t)b * S_;
    const size_t hoff = (size_t)h * HD_;

    auto stage = [&](int kv, int buf) {
#pragma unroll
        for (int s = 0; s < 2; s++) {
            const int cb = s * 256 + wave * 64;
            const int c  = cb + lane;
            const int row = c >> 3;
            const int gc  = (c & 7) ^ (row & 7);
            __builtin_amdgcn_global_load_lds(
                GPTR(Kb + (size_t)(tok0 + kv + row) * QKS + hoff + gc * 8),
                LPTR(&Ks[buf][cb * 8]), 16, 0, 0);
            __builtin_amdgcn_global_load_lds(
                GPTR(VT + (hoff + row) * (size_t)NTOK + tok0 + kv + gc * 8),
                LPTR(&Vs[buf][cb * 8]), 16, 0, 0);
        }
    };

#pragma unroll 1
    for (int sidx = 0; sidx < 2; sidx++) {
        const int qt = sidx == 0 ? blockIdx.x : 15 - blockIdx.x;
        const int qb = qt * 128;
        const int q0 = qb + wave * 32;

        // Q as B-operand: B[k=hd=quad*8+j][n=q=l16] — 16B contiguous loads
        bf16x8 qf[2][2];
#pragma unroll
        for (int qi = 0; qi < 2; qi++)
#pragma unroll
            for (int ks = 0; ks < 2; ks++)
                qf[qi][ks] = *(const bf16x8*)&Qb[(tok0 + q0 + qi * 16 + l16) * QKS +
                                                 hoff + ks * 32 + quad * 8];

        f32x4 oacc[2][4] = {};     // O^T[hd = hs*16+quad*4+r][q = qi*16+l16]
        float lsum[2] = {0.f, 0.f};
        const int ktb = (qb + 127) >> 6;

        stage(0, 0);
        __syncthreads();

        for (int kt = 0; kt <= ktb; kt++) {
            const int cur = kt & 1;
            const int kv0 = kt * 64;
            if (kt < ktb) stage(kv0 + 64, 1 - cur);   // prefetch overlaps compute

            if (kv0 <= q0 + 31) {
                // S^T = K(A) · Q(B):  st[qi][ksub] rows kv=quad*4+r, col q=l16
                f32x4 st[2][4] = {};
#pragma unroll
                for (int ks = 0; ks < 2; ks++)
#pragma unroll
                    for (int ksub = 0; ksub < 4; ksub++) {
                        const int r = ksub * 16 + l16;
                        bf16x8 kf = *(const bf16x8*)
                            &Ks[cur][(r * 8 + (((ks * 4 + quad) ^ (r & 7)))) * 8];
#pragma unroll
                        for (int qi = 0; qi < 2; qi++)
                            st[qi][ksub] = __builtin_amdgcn_mfma_f32_16x16x32_bf16(
                                kf, qf[qi][ks], st[qi][ksub], 0, 0, 0);
                    }
                if (kv0 + 63 > q0) {   // diagonal tiles: causal mask on S^T
#pragma unroll
                    for (int qi = 0; qi < 2; qi++)
#pragma unroll
                        for (int ksub = 0; ksub < 4; ksub++)
#pragma unroll
                            for (int r = 0; r < 4; r++) {
                                const int kg = kv0 + ksub * 16 + quad * 4 + r;
                                const int qg = q0 + qi * 16 + l16;
                                if (kg > qg) st[qi][ksub][r] = -1e30f;
                            }
                }
                // p = exp2(s) (Q pre-scaled); pack P^T into B-frags (registers!)
                short4v pfrag[2][4];
#pragma unroll
                for (int qi = 0; qi < 2; qi++)
#pragma unroll
                    for (int ksub = 0; ksub < 4; ksub++) {
                        float p0 = __builtin_amdgcn_exp2f(st[qi][ksub][0]);
                        float p1 = __builtin_amdgcn_exp2f(st[qi][ksub][1]);
                        float p2 = __builtin_amdgcn_exp2f(st[qi][ksub][2]);
                        float p3 = __builtin_amdgcn_exp2f(st[qi][ksub][3]);
                        lsum[qi] += (p0 + p1) + (p2 + p3);
                        short4v pf = {bf16_bits(p0), bf16_bits(p1),
                                      bf16_bits(p2), bf16_bits(p3)};
                        pfrag[qi][ksub] = pf;
                    }
                // O^T += V^T(A) · P^T(B), K=16 MFMAs; V A-frag = 8B LDS reads
#pragma unroll
                for (int ksub = 0; ksub < 4; ksub++)
#pragma unroll
                    for (int hs = 0; hs < 4; hs++) {
                        const int row = hs * 16 + l16;
                        const int swz = (ksub * 2 + (quad >> 1)) ^ (row & 7);
                        short4v vf = *(const short4v*)
                            &Vs[cur][row * 64 + swz * 8 + (quad & 1) * 4];
#pragma unroll
                        for (int qi = 0; qi < 2; qi++)
                            oacc[qi][hs] = __builtin_amdgcn_mfma_f32_16x16x16bf16_1k(
                                vf, pfrag[qi][ksub], oacc[qi][hs], 0, 0, 0);
                    }
            }
            __syncthreads();   // buf[cur] readers done; prefetch drained
        }

        // l: reduce over quad lanes; O^T cols already live at q = qi*16+l16
#pragma unroll
        for (int qi = 0; qi < 2; qi++) {
            float v = lsum[qi];
            v += __shfl_xor(v, 16);
            v += __shfl_xor(v, 32);
            const float rl = 1.0f / v;
            // epilogue: ctx[tok][hd] — r contiguous in hd -> 8B stores
#pragma unroll
            for (int hs = 0; hs < 4; hs++) {
                bf16x4 o;
#pragma unroll
                for (int r = 0; r < 4; r++) o[r] = (__bf16)(oacc[qi][hs][r] * rl);
                *(bf16x4*)&ctx[(tok0 + q0 + qi * 16 + l16) * D_ + hoff +
                               hs * 16 + quad * 4] = o;
            }
        }
    }
}

// ---------------- launch ----------------
extern "C" void kernel_launch(void* const* d_in, const int* in_sizes, int n_in,
                              void* d_out, int out_size, void* d_ws, size_t ws_size,
                              hipStream_t stream) {
    const float* x  = (const float*)d_in[0];
    const float* Wq = (const float*)d_in[1];
    const float* Wk = (const float*)d_in[2];
    const float* Wv = (const float*)d_in[3];
    const float* Wo = (const float*)d_in[4];
    const float* bo = (const float*)d_in[5];
    float* out = (float*)d_out;

    char* p = (char*)d_ws;
    __bf16* xb   = (__bf16*)p; p += (size_t)NTOK * D_ * 2;   // 16 MB
    __bf16* wqkt = (__bf16*)p; p += (size_t)2 * D_ * D_ * 2; // 4 MB
    __bf16* wvt  = (__bf16*)p; p += (size_t)D_ * D_ * 2;     // 2 MB
    __bf16* wot  = (__bf16*)p; p += (size_t)D_ * D_ * 2;     // 2 MB
    __bf16* qk   = (__bf16*)p; p += (size_t)NTOK * QKS * 2;  // 32 MB [tok][Q|K]
    __bf16* VT   = (__bf16*)p; p += (size_t)NTOK * D_ * 2;   // 16 MB [d][tok]
    __bf16* ctx  = (__bf16*)p; p += (size_t)NTOK * D_ * 2;   // 16 MB

    k_prep<<<dim3(4096 + 4 * 1024), 256, 0, stream>>>(x, xb, Wq, Wk, Wv, Wo,
                                                      wqkt, wvt, wot);
    k_gemm_qkv<<<dim3(1024 + 512), 256, 0, stream>>>(xb, wqkt, wvt, qk, VT);
    k_attn<<<dim3(8, H_, 4), 256, 0, stream>>>(qk, qk + D_, VT, ctx);
    k_gemm_o<<<dim3(64, 8), 256, 0, stream>>>(ctx, wot, out, bo);
}

// Round 7
// 241.279 us; speedup vs baseline: 1.3773x; 1.0395x over previous
//
#include <hip/hip_runtime.h>

#define S_   2048
#define D_   1024
#define H_   16
#define HD_  64
#define NTOK 8192   // B*S
#define QKS  2048   // row stride of fused QK output
#define QSCALE 0.18033688f  // 0.125 * log2(e) — folded into Q at projection time

typedef __attribute__((ext_vector_type(8))) __bf16 bf16x8;
typedef __attribute__((ext_vector_type(4))) __bf16 bf16x4;
typedef __attribute__((ext_vector_type(4))) float  f32x4;
typedef __attribute__((ext_vector_type(4))) short  short4v;

#define GPTR(p) ((__attribute__((address_space(1))) void*)(unsigned long long)(p))
#define LPTR(p) ((__attribute__((address_space(3))) void*)(p))

// ---------------- fused prep: cast x -> bf16, transpose 4 weights ----------------
__global__ __launch_bounds__(256) void k_prep(const float* __restrict__ x,
                                              __bf16* __restrict__ xb,
                                              const float* __restrict__ Wq,
                                              const float* __restrict__ Wk,
                                              const float* __restrict__ Wv,
                                              const float* __restrict__ Wo,
                                              __bf16* __restrict__ wqkt,
                                              __bf16* __restrict__ wvt,
                                              __bf16* __restrict__ wot) {
    const int bx = blockIdx.x;
    if (bx < 4096) {
        int i = bx * 2048 + threadIdx.x * 8;
        f32x4 a = *(const f32x4*)(x + i);
        f32x4 b = *(const f32x4*)(x + i + 4);
        bf16x8 o;
#pragma unroll
        for (int j = 0; j < 4; j++) { o[j] = (__bf16)a[j]; o[4 + j] = (__bf16)b[j]; }
        *(bf16x8*)(xb + i) = o;
        return;
    }
    __shared__ float t[32][33];
    const int tt = bx - 4096;
    const int widx = tt >> 10, r = tt & 1023;
    const float* W;
    __bf16* Wt;
    switch (widx) {
        case 0: W = Wq; Wt = wqkt; break;
        case 1: W = Wk; Wt = wqkt + (size_t)D_ * D_; break;
        case 2: W = Wv; Wt = wvt; break;
        default: W = Wo; Wt = wot; break;
    }
    const int i0 = (r & 31) * 32, j0 = (r >> 5) * 32;
    const int tx = threadIdx.x & 31, ty = threadIdx.x >> 5;
#pragma unroll
    for (int rr = 0; rr < 32; rr += 8)
        t[ty + rr][tx] = W[(size_t)(i0 + ty + rr) * D_ + j0 + tx];
    __syncthreads();
#pragma unroll
    for (int rr = 0; rr < 32; rr += 8)
        Wt[(size_t)(j0 + ty + rr) * D_ + i0 + tx] = (__bf16)t[tx][ty + rr];
}

// ---------------- shared GEMM body (bf16 out, optional scale) ----------------
// LDS k-chunk XOR-swizzle by (row>>1)&3: fragment ds_read_b128 banks go from
// 8-way aliased (2 windows x 8 lanes) to 2-way (8 windows x 2 lanes) = free.
__device__ __forceinline__ void gemm_body_bf16(const __bf16* __restrict__ A,
                                               const __bf16* __restrict__ Bt,
                                               __bf16* __restrict__ C,
                                               int N, int K, int tm, int tn,
                                               float scale,
                                               __bf16* As, __bf16* Bs) {
    const int tid  = threadIdx.x;
    const int wave = tid >> 6, lane = tid & 63;
    const int quad = lane >> 4, l16 = lane & 15;
    const int wm = (wave & 1) * 64, wn = (wave >> 1) * 64;
    f32x4 acc[4][4] = {};

    for (int k0 = 0; k0 < K; k0 += 32) {
        __syncthreads();
#pragma unroll
        for (int s = 0; s < 2; s++) {
            const int cb = s * 256 + wave * 64;
            const int c  = cb + lane;
            const int row = c >> 2;
            const int kc  = ((c & 3) ^ ((row >> 1) & 3)) * 8;  // swizzled k-chunk
            __builtin_amdgcn_global_load_lds(GPTR(A + (size_t)(tm + row) * K + k0 + kc),
                                             LPTR(As + cb * 8), 16, 0, 0);
            __builtin_amdgcn_global_load_lds(GPTR(Bt + (size_t)(tn + row) * K + k0 + kc),
                                             LPTR(Bs + cb * 8), 16, 0, 0);
        }
        __syncthreads();

        bf16x8 af[4], bf[4];
#pragma unroll
        for (int mi = 0; mi < 4; mi++) {
            const int rf = wm + mi * 16 + l16;
            af[mi] = *(const bf16x8*)&As[rf * 32 + (quad ^ ((rf >> 1) & 3)) * 8];
        }
#pragma unroll
        for (int ni = 0; ni < 4; ni++) {
            const int rf = wn + ni * 16 + l16;
            bf[ni] = *(const bf16x8*)&Bs[rf * 32 + (quad ^ ((rf >> 1) & 3)) * 8];
        }
#pragma unroll
        for (int mi = 0; mi < 4; mi++)
#pragma unroll
            for (int ni = 0; ni < 4; ni++)
                acc[mi][ni] = __builtin_amdgcn_mfma_f32_16x16x32_bf16(
                    af[mi], bf[ni], acc[mi][ni], 0, 0, 0);
    }

#pragma unroll
    for (int mi = 0; mi < 4; mi++)
#pragma unroll
        for (int ni = 0; ni < 4; ni++)
#pragma unroll
            for (int r = 0; r < 4; r++) {
                const int row = tm + wm + mi * 16 + quad * 4 + r;
                const int col = tn + wn + ni * 16 + l16;
                C[(size_t)row * N + col] = (__bf16)(acc[mi][ni][r] * scale);
            }
}

// ---------------- fused QKV projection ----------------
__global__ __launch_bounds__(256) void k_gemm_qkv(const __bf16* __restrict__ xb,
                                                  const __bf16* __restrict__ wqkt,
                                                  const __bf16* __restrict__ wvt,
                                                  __bf16* __restrict__ qk,
                                                  __bf16* __restrict__ VT) {
    __shared__ __bf16 As[128 * 32];
    __shared__ __bf16 Bs[128 * 32];
    const int bx = blockIdx.x;
    if (bx < 1024) {
        const int tm = (bx & 63) * 128, tn = (bx >> 6) * 128;
        const float scale = (tn < D_) ? QSCALE : 1.0f;
        gemm_body_bf16(xb, wqkt, qk, QKS, D_, tm, tn, scale, As, Bs);
    } else {
        const int b2 = bx - 1024;
        const int tm = (b2 & 7) * 128, tn = (b2 >> 3) * 128;
        gemm_body_bf16(wvt, xb, VT, NTOK, D_, tm, tn, 1.0f, As, Bs);
    }
}

// ---------------- output GEMM: out = ctx Wo + bo (fp32 epilogue) ----------------
__global__ __launch_bounds__(256) void k_gemm_o(const __bf16* __restrict__ A,
                                                const __bf16* __restrict__ Bt,
                                                float* __restrict__ C,
                                                const float* __restrict__ bias) {
    __shared__ __bf16 As[128 * 32];
    __shared__ __bf16 Bs[128 * 32];
    const int tid  = threadIdx.x;
    const int wave = tid >> 6, lane = tid & 63;
    const int quad = lane >> 4, l16 = lane & 15;
    const int tm = blockIdx.x * 128, tn = blockIdx.y * 128;
    const int wm = (wave & 1) * 64, wn = (wave >> 1) * 64;
    const int N = D_, K = D_;
    f32x4 acc[4][4] = {};

    for (int k0 = 0; k0 < K; k0 += 32) {
        __syncthreads();
#pragma unroll
        for (int s = 0; s < 2; s++) {
            const int cb = s * 256 + wave * 64;
            const int c  = cb + lane;
            const int row = c >> 2;
            const int kc  = ((c & 3) ^ ((row >> 1) & 3)) * 8;  // swizzled k-chunk
            __builtin_amdgcn_global_load_lds(GPTR(A + (size_t)(tm + row) * K + k0 + kc),
                                             LPTR(As + cb * 8), 16, 0, 0);
            __builtin_amdgcn_global_load_lds(GPTR(Bt + (size_t)(tn + row) * K + k0 + kc),
                                             LPTR(Bs + cb * 8), 16, 0, 0);
        }
        __syncthreads();

        bf16x8 af[4], bf[4];
#pragma unroll
        for (int mi = 0; mi < 4; mi++) {
            const int rf = wm + mi * 16 + l16;
            af[mi] = *(const bf16x8*)&As[rf * 32 + (quad ^ ((rf >> 1) & 3)) * 8];
        }
#pragma unroll
        for (int ni = 0; ni < 4; ni++) {
            const int rf = wn + ni * 16 + l16;
            bf[ni] = *(const bf16x8*)&Bs[rf * 32 + (quad ^ ((rf >> 1) & 3)) * 8];
        }
#pragma unroll
        for (int mi = 0; mi < 4; mi++)
#pragma unroll
            for (int ni = 0; ni < 4; ni++)
                acc[mi][ni] = __builtin_amdgcn_mfma_f32_16x16x32_bf16(
                    af[mi], bf[ni], acc[mi][ni], 0, 0, 0);
    }

#pragma unroll
    for (int mi = 0; mi < 4; mi++)
#pragma unroll
        for (int ni = 0; ni < 4; ni++)
#pragma unroll
            for (int r = 0; r < 4; r++) {
                const int row = tm + wm + mi * 16 + quad * 4 + r;
                const int col = tn + wn + ni * 16 + l16;
                C[(size_t)row * N + col] = acc[mi][ni][r] + bias[col];
            }
}

__device__ __forceinline__ short bf16_bits(float f) {
    __bf16 h = (__bf16)f;
    return __builtin_bit_cast(short, h);
}

// ---------------- causal flash attention (R6 structure, unchanged) ----------------
__global__ __launch_bounds__(256, 2) void k_attn(const __bf16* __restrict__ Qb,
                                                 const __bf16* __restrict__ Kb,
                                                 const __bf16* __restrict__ VT,
                                                 __bf16* __restrict__ ctx) {
    __shared__ __bf16 Ks[2][64 * 64];   // [kv][hd], 16B-chunk XOR-swizzled
    __shared__ __bf16 Vs[2][64 * 64];   // [hd][kv], 16B-chunk XOR-swizzled

    const int tid = threadIdx.x;
    const int wave = tid >> 6, lane = tid & 63;
    const int quad = lane >> 4, l16 = lane & 15;
    const int h = blockIdx.y, b = blockIdx.z;
    const size_t tok0 = (size_t)b * S_;
    const size_t hoff = (size_t)h * HD_;

    auto stage = [&](int kv, int buf) {
#pragma unroll
        for (int s = 0; s < 2; s++) {
            const int cb = s * 256 + wave * 64;
            const int c  = cb + lane;
            const int row = c >> 3;
            const int gc  = (c & 7) ^ (row & 7);
            __builtin_amdgcn_global_load_lds(
                GPTR(Kb + (size_t)(tok0 + kv + row) * QKS + hoff + gc * 8),
                LPTR(&Ks[buf][cb * 8]), 16, 0, 0);
            __builtin_amdgcn_global_load_lds(
                GPTR(VT + (hoff + row) * (size_t)NTOK + tok0 + kv + gc * 8),
                LPTR(&Vs[buf][cb * 8]), 16, 0, 0);
        }
    };

#pragma unroll 1
    for (int sidx = 0; sidx < 2; sidx++) {
        const int qt = sidx == 0 ? blockIdx.x : 15 - blockIdx.x;
        const int qb = qt * 128;
        const int q0 = qb + wave * 32;

        // Q as B-operand: B[k=hd=quad*8+j][n=q=l16]
        bf16x8 qf[2][2];
#pragma unroll
        for (int qi = 0; qi < 2; qi++)
#pragma unroll
            for (int ks = 0; ks < 2; ks++)
                qf[qi][ks] = *(const bf16x8*)&Qb[(tok0 + q0 + qi * 16 + l16) * QKS +
                                                 hoff + ks * 32 + quad * 8];

        f32x4 oacc[2][4] = {};     // O^T[hd = hs*16+quad*4+r][q = qi*16+l16]
        float lsum[2] = {0.f, 0.f};
        const int ktb = (qb + 127) >> 6;

        stage(0, 0);
        __syncthreads();

        for (int kt = 0; kt <= ktb; kt++) {
            const int cur = kt & 1;
            const int kv0 = kt * 64;
            if (kt < ktb) stage(kv0 + 64, 1 - cur);   // prefetch overlaps compute

            if (kv0 <= q0 + 31) {
                // S^T = K(A) · Q(B)
                f32x4 st[2][4] = {};
#pragma unroll
                for (int ks = 0; ks < 2; ks++)
#pragma unroll
                    for (int ksub = 0; ksub < 4; ksub++) {
                        const int r = ksub * 16 + l16;
                        bf16x8 kf = *(const bf16x8*)
                            &Ks[cur][(r * 8 + (((ks * 4 + quad) ^ (r & 7)))) * 8];
#pragma unroll
                        for (int qi = 0; qi < 2; qi++)
                            st[qi][ksub] = __builtin_amdgcn_mfma_f32_16x16x32_bf16(
                                kf, qf[qi][ks], st[qi][ksub], 0, 0, 0);
                    }
                if (kv0 + 63 > q0) {   // diagonal tiles: causal mask on S^T
#pragma unroll
                    for (int qi = 0; qi < 2; qi++)
#pragma unroll
                        for (int ksub = 0; ksub < 4; ksub++)
#pragma unroll
                            for (int r = 0; r < 4; r++) {
                                const int kg = kv0 + ksub * 16 + quad * 4 + r;
                                const int qg = q0 + qi * 16 + l16;
                                if (kg > qg) st[qi][ksub][r] = -1e30f;
                            }
                }
                // p = exp2(s); pack P^T into B-frags (registers)
                short4v pfrag[2][4];
#pragma unroll
                for (int qi = 0; qi < 2; qi++)
#pragma unroll
                    for (int ksub = 0; ksub < 4; ksub++) {
                        float p0 = __builtin_amdgcn_exp2f(st[qi][ksub][0]);
                        float p1 = __builtin_amdgcn_exp2f(st[qi][ksub][1]);
                        float p2 = __builtin_amdgcn_exp2f(st[qi][ksub][2]);
                        float p3 = __builtin_amdgcn_exp2f(st[qi][ksub][3]);
                        lsum[qi] += (p0 + p1) + (p2 + p3);
                        short4v pf = {bf16_bits(p0), bf16_bits(p1),
                                      bf16_bits(p2), bf16_bits(p3)};
                        pfrag[qi][ksub] = pf;
                    }
                // O^T += V^T(A) · P^T(B), K=16 MFMAs
#pragma unroll
                for (int ksub = 0; ksub < 4; ksub++)
#pragma unroll
                    for (int hs = 0; hs < 4; hs++) {
                        const int row = hs * 16 + l16;
                        const int swz = (ksub * 2 + (quad >> 1)) ^ (row & 7);
                        short4v vf = *(const short4v*)
                            &Vs[cur][row * 64 + swz * 8 + (quad & 1) * 4];
#pragma unroll
                        for (int qi = 0; qi < 2; qi++)
                            oacc[qi][hs] = __builtin_amdgcn_mfma_f32_16x16x16bf16_1k(
                                vf, pfrag[qi][ksub], oacc[qi][hs], 0, 0, 0);
                    }
            }
            __syncthreads();
        }

        // l reduce + epilogue (8B stores, r contiguous in hd)
#pragma unroll
        for (int qi = 0; qi < 2; qi++) {
            float v = lsum[qi];
            v += __shfl_xor(v, 16);
            v += __shfl_xor(v, 32);
            const float rl = 1.0f / v;
#pragma unroll
            for (int hs = 0; hs < 4; hs++) {
                bf16x4 o;
#pragma unroll
                for (int r = 0; r < 4; r++) o[r] = (__bf16)(oacc[qi][hs][r] * rl);
                *(bf16x4*)&ctx[(tok0 + q0 + qi * 16 + l16) * D_ + hoff +
                               hs * 16 + quad * 4] = o;
            }
        }
    }
}

// ---------------- launch ----------------
extern "C" void kernel_launch(void* const* d_in, const int* in_sizes, int n_in,
                              void* d_out, int out_size, void* d_ws, size_t ws_size,
                              hipStream_t stream) {
    const float* x  = (const float*)d_in[0];
    const float* Wq = (const float*)d_in[1];
    const float* Wk = (const float*)d_in[2];
    const float* Wv = (const float*)d_in[3];
    const float* Wo = (const float*)d_in[4];
    const float* bo = (const float*)d_in[5];
    float* out = (float*)d_out;

    char* p = (char*)d_ws;
    __bf16* xb   = (__bf16*)p; p += (size_t)NTOK * D_ * 2;   // 16 MB
    __bf16* wqkt = (__bf16*)p; p += (size_t)2 * D_ * D_ * 2; // 4 MB
    __bf16* wvt  = (__bf16*)p; p += (size_t)D_ * D_ * 2;     // 2 MB
    __bf16* wot  = (__bf16*)p; p += (size_t)D_ * D_ * 2;     // 2 MB
    __bf16* qk   = (__bf16*)p; p += (size_t)NTOK * QKS * 2;  // 32 MB [tok][Q|K]
    __bf16* VT   = (__bf16*)p; p += (size_t)NTOK * D_ * 2;   // 16 MB [d][tok]
    __bf16* ctx  = (__bf16*)p; p += (size_t)NTOK * D_ * 2;   // 16 MB

    k_prep<<<dim3(4096 + 4 * 1024), 256, 0, stream>>>(x, xb, Wq, Wk, Wv, Wo,
                                                      wqkt, wvt, wot);
    k_gemm_qkv<<<dim3(1024 + 512), 256, 0, stream>>>(xb, wqkt, wvt, qk, VT);
    k_attn<<<dim3(8, H_, 4), 256, 0, stream>>>(qk, qk + D_, VT, ctx);
    k_gemm_o<<<dim3(64, 8), 256, 0, stream>>>(ctx, wot, out, bo);
}